// Round 13
// baseline (30.799 us; speedup 1.0000x reference)
//
#include <hip/hip_runtime.h>

namespace {

constexpr float kDT = 1e-3f;
constexpr int kB = 512;
constexpr int kT = 8192;
constexpr int kThreads = 1024;
constexpr int kWaves = kThreads / 64;     // 16
constexpr int kSteps = 4;                 // consecutive steps per thread
constexpr int kPassSteps = kSteps * kThreads;  // 4096 steps per pass
constexpr int kPasses = kT / kPassSteps;  // 2

// Affine transform x' = M x + b packed {a,b,c,d,p,q}
struct Xf { float a, b, c, d, p, q; };

// Apply e (earlier) first, then l (later).
__device__ __forceinline__ Xf comp(const Xf& e, const Xf& l) {
  Xf o;
  o.a = l.a * e.a + l.b * e.c;
  o.b = l.a * e.b + l.b * e.d;
  o.c = l.c * e.a + l.d * e.c;
  o.d = l.c * e.b + l.d * e.d;
  o.p = l.a * e.p + l.b * e.q + l.p;
  o.q = l.c * e.p + l.d * e.q + l.q;
  return o;
}

// DPP move with per-component identity fallback: lanes whose source is
// invalid (bound_ctrl=false) or masked off by RowMask keep `old`.
template <int Ctrl, int RowMask>
__device__ __forceinline__ float dpp1(float v, float old) {
  return __int_as_float(__builtin_amdgcn_update_dpp(
      __float_as_int(old), __float_as_int(v), Ctrl, RowMask, 0xf, false));
}

// Shifted transform with identity in invalid/masked lanes -> compose is
// unconditionally safe (comp(I, x) == x). Pure VALU, no LDS.
template <int Ctrl, int RowMask>
__device__ __forceinline__ Xf dpp_xf(const Xf& v) {
  Xf r;
  r.a = dpp1<Ctrl, RowMask>(v.a, 1.0f);
  r.b = dpp1<Ctrl, RowMask>(v.b, 0.0f);
  r.c = dpp1<Ctrl, RowMask>(v.c, 0.0f);
  r.d = dpp1<Ctrl, RowMask>(v.d, 1.0f);
  r.p = dpp1<Ctrl, RowMask>(v.p, 0.0f);
  r.q = dpp1<Ctrl, RowMask>(v.q, 0.0f);
  return r;
}

// Canonical GCN wave64 inclusive scan: row_shr 1/2/4/8, bcast15 -> rows 1&3,
// bcast31 -> rows 2&3. 36 v_mov_dpp total, zero DS ops.
__device__ __forceinline__ Xf wave_incl_scan(Xf x) {
  x = comp(dpp_xf<0x111, 0xf>(x), x);  // row_shr:1
  x = comp(dpp_xf<0x112, 0xf>(x), x);  // row_shr:2
  x = comp(dpp_xf<0x114, 0xf>(x), x);  // row_shr:4
  x = comp(dpp_xf<0x118, 0xf>(x), x);  // row_shr:8
  x = comp(dpp_xf<0x142, 0xa>(x), x);  // row_bcast:15 -> rows 1,3
  x = comp(dpp_xf<0x143, 0xc>(x), x);  // row_bcast:31 -> rows 2,3
  return x;
}

__device__ __forceinline__ Xf readlane_xf(const Xf& v, int l) {
  Xf r;
  r.a = __int_as_float(__builtin_amdgcn_readlane(__float_as_int(v.a), l));
  r.b = __int_as_float(__builtin_amdgcn_readlane(__float_as_int(v.b), l));
  r.c = __int_as_float(__builtin_amdgcn_readlane(__float_as_int(v.c), l));
  r.d = __int_as_float(__builtin_amdgcn_readlane(__float_as_int(v.d), l));
  r.p = __int_as_float(__builtin_amdgcn_readlane(__float_as_int(v.p), l));
  r.q = __int_as_float(__builtin_amdgcn_readlane(__float_as_int(v.q), l));
  return r;
}

__device__ __forceinline__ Xf make_xf(const float4 xv, float d0, float d1,
                                      float A00, float A01, float A10, float A11,
                                      float C00, float C01, float C10, float C11) {
  Xf m;
  m.a = 1.0f + kDT * (A00 - (xv.x * C00 + xv.y * C10));
  m.b =        kDT * (A01 - (xv.x * C01 + xv.y * C11));
  m.c =        kDT * (A10 - (xv.z * C00 + xv.w * C10));
  m.d = 1.0f + kDT * (A11 - (xv.z * C01 + xv.w * C11));
  m.p = xv.x * d0 + xv.y * d1;
  m.q = xv.z * d0 + xv.w * d1;
  return m;
}

// One block per batch row; 2 passes of 4096 steps; 4 consecutive steps per
// thread. Scan machinery (wave DPP scan + stitch) paid only twice per block.
__global__ __launch_bounds__(kThreads) void k_fused(
    const float* __restrict__ xic, const float* __restrict__ dy,
    const float* __restrict__ Ap, const float* __restrict__ Cp,
    float* __restrict__ out) {
  __shared__ float sWT[2][kWaves][6];

  const int tid = threadIdx.x;
  const int lane = tid & 63;
  const int w = tid >> 6;
  const size_t rbase = (size_t)blockIdx.x * kT;        // xic float4 index
  const size_t rbase2 = (size_t)blockIdx.x * (kT / 2); // dy/out float4 index

  const float4* X4 = reinterpret_cast<const float4*>(xic);
  const float4* D4 = reinterpret_cast<const float4*>(dy);
  float4* O4 = reinterpret_cast<float4*>(out);

  const float A00 = Ap[0], A01 = Ap[1], A10 = Ap[2], A11 = Ap[3];
  const float C00 = Cp[0], C01 = Cp[1], C10 = Cp[2], C11 = Cp[3];

  float4 xv[2][kSteps];   // per-pass xic rows, double-buffered
  float4 dv[2][2];        // per-pass dy (2 float4 = 4 steps)

  // Prefetch pass 0.
  {
    const size_t sx = (size_t)kSteps * tid;
#pragma unroll
    for (int k = 0; k < kSteps; ++k) xv[0][k] = X4[rbase + sx + k];
    const size_t sd = (size_t)2 * tid;
    dv[0][0] = D4[rbase2 + sd];
    dv[0][1] = D4[rbase2 + sd + 1];
  }

  float x0 = 1.0f, x1 = 0.0f;  // row state entering current pass

#pragma unroll
  for (int c = 0; c < kPasses; ++c) {
    const int buf = c & 1;
    // Prefetch next pass before any barrier/scan of this pass.
    if (c + 1 < kPasses) {
      const size_t sx = (size_t)(c + 1) * kPassSteps + (size_t)kSteps * tid;
#pragma unroll
      for (int k = 0; k < kSteps; ++k) xv[buf ^ 1][k] = X4[rbase + sx + k];
      const size_t sd = (size_t)(c + 1) * (kPassSteps / 2) + 2 * tid;
      dv[buf ^ 1][0] = D4[rbase2 + sd];
      dv[buf ^ 1][1] = D4[rbase2 + sd + 1];
    }

    // Per-step transforms for this thread's 4 steps.
    Xf s[kSteps];
    s[0] = make_xf(xv[buf][0], dv[buf][0].x, dv[buf][0].y,
                   A00, A01, A10, A11, C00, C01, C10, C11);
    s[1] = make_xf(xv[buf][1], dv[buf][0].z, dv[buf][0].w,
                   A00, A01, A10, A11, C00, C01, C10, C11);
    s[2] = make_xf(xv[buf][2], dv[buf][1].x, dv[buf][1].y,
                   A00, A01, A10, A11, C00, C01, C10, C11);
    s[3] = make_xf(xv[buf][3], dv[buf][1].z, dv[buf][1].w,
                   A00, A01, A10, A11, C00, C01, C10, C11);

    // Serial compose: thread total = s3 ∘ s2 ∘ s1 ∘ s0.
    Xf tot = comp(s[0], s[1]);
    tot = comp(tot, s[2]);
    tot = comp(tot, s[3]);

    // Wave-level inclusive scan over thread totals (pure VALU/DPP).
    const Xf inc = wave_incl_scan(tot);

    if (lane == 63) {
      sWT[buf][w][0] = inc.a; sWT[buf][w][1] = inc.b; sWT[buf][w][2] = inc.c;
      sWT[buf][w][3] = inc.d; sWT[buf][w][4] = inc.p; sWT[buf][w][5] = inc.q;
    }
    __syncthreads();  // the only barrier this pass (sWT double-buffered)

    // Every wave redundantly: lanes 0..15 read the 16 wave totals
    // (conflict-free: stride 6 dwords), 4-round DPP scan, readlane bcast.
    Xf v{1.f, 0.f, 0.f, 1.f, 0.f, 0.f};
    if (lane < kWaves) {
      v = Xf{sWT[buf][lane][0], sWT[buf][lane][1], sWT[buf][lane][2],
             sWT[buf][lane][3], sWT[buf][lane][4], sWT[buf][lane][5]};
    }
    v = comp(dpp_xf<0x111, 0xf>(v), v);
    v = comp(dpp_xf<0x112, 0xf>(v), v);
    v = comp(dpp_xf<0x114, 0xf>(v), v);
    v = comp(dpp_xf<0x118, 0xf>(v), v);

    const Xf TT = readlane_xf(v, kWaves - 1);           // pass total
    Xf Ew{1.f, 0.f, 0.f, 1.f, 0.f, 0.f};
    if (w > 0) Ew = readlane_xf(v, w - 1);              // wave-uniform branch

    // Lane-exclusive prefix: whole-wave shift right by 1 (WF_SR1).
    const Xf le = dpp_xf<0x138, 0xf>(inc);              // lane0 -> identity

    const Xf ex = comp(Ew, le);  // block-exclusive prefix for this thread

    // State entering this thread's first step.
    float e0 = ex.a * x0 + ex.b * x1 + ex.p;
    float e1 = ex.c * x0 + ex.d * x1 + ex.q;

    // Emit 4 outputs (pre-update states) as 2 coalesced-class float4 stores.
    const size_t ob = rbase2 + (size_t)c * (kPassSteps / 2) + 2 * tid;
#pragma unroll
    for (int h = 0; h < 2; ++h) {
      float4 o;
      o.x = kDT * (C00 * e0 + C01 * e1);
      o.y = kDT * (C10 * e0 + C11 * e1);
      {
        const Xf& st = s[2 * h];
        const float n0 = st.a * e0 + st.b * e1 + st.p;
        const float n1 = st.c * e0 + st.d * e1 + st.q;
        e0 = n0; e1 = n1;
      }
      o.z = kDT * (C00 * e0 + C01 * e1);
      o.w = kDT * (C10 * e0 + C11 * e1);
      {
        const Xf& st = s[2 * h + 1];
        const float n0 = st.a * e0 + st.b * e1 + st.p;
        const float n1 = st.c * e0 + st.d * e1 + st.q;
        e0 = n0; e1 = n1;
      }
      O4[ob + h] = o;
    }

    // Advance row state by the whole pass (identical in all threads).
    if (c + 1 < kPasses) {
      const float n0 = TT.a * x0 + TT.b * x1 + TT.p;
      const float n1 = TT.c * x0 + TT.d * x1 + TT.q;
      x0 = n0; x1 = n1;
    }
  }
}

}  // namespace

extern "C" void kernel_launch(void* const* d_in, const int* in_sizes, int n_in,
                              void* d_out, int out_size, void* d_ws,
                              size_t ws_size, hipStream_t stream) {
  const float* xic = (const float*)d_in[0];  // [B,T,2,2]
  const float* dy  = (const float*)d_in[1];  // [B,T,2]
  const float* Ap  = (const float*)d_in[2];  // [2,2] coeffs_A
  const float* Cp  = (const float*)d_in[3];  // [2,2] C
  float* out = (float*)d_out;                // [B,T,2]

  k_fused<<<kB, kThreads, 0, stream>>>(xic, dy, Ap, Cp, out);
}

// Round 14
// 29.983 us; speedup vs baseline: 1.0272x; 1.0272x over previous
//
#include <hip/hip_runtime.h>

namespace {

constexpr float kDT = 1e-3f;
constexpr int kB = 512;
constexpr int kT = 8192;
constexpr int kThreads = 1024;
constexpr int kWaves = kThreads / 64;   // 16

// Affine transform x' = M x + b packed {a,b,c,d,p,q}
struct Xf { float a, b, c, d, p, q; };

// Apply e (earlier) first, then l (later).
__device__ __forceinline__ Xf comp(const Xf& e, const Xf& l) {
  Xf o;
  o.a = l.a * e.a + l.b * e.c;
  o.b = l.a * e.b + l.b * e.d;
  o.c = l.c * e.a + l.d * e.c;
  o.d = l.c * e.b + l.d * e.d;
  o.p = l.a * e.p + l.b * e.q + l.p;
  o.q = l.c * e.p + l.d * e.q + l.q;
  return o;
}

// DPP move with per-component identity fallback: lanes whose source is
// invalid (bound_ctrl=false) or masked off by RowMask keep `old`.
template <int Ctrl, int RowMask>
__device__ __forceinline__ float dpp1(float v, float old) {
  return __int_as_float(__builtin_amdgcn_update_dpp(
      __float_as_int(old), __float_as_int(v), Ctrl, RowMask, 0xf, false));
}

// Shifted transform with identity in invalid/masked lanes -> compose is
// unconditionally safe (comp(I, x) == x). Pure VALU, no LDS.
template <int Ctrl, int RowMask>
__device__ __forceinline__ Xf dpp_xf(const Xf& v) {
  Xf r;
  r.a = dpp1<Ctrl, RowMask>(v.a, 1.0f);
  r.b = dpp1<Ctrl, RowMask>(v.b, 0.0f);
  r.c = dpp1<Ctrl, RowMask>(v.c, 0.0f);
  r.d = dpp1<Ctrl, RowMask>(v.d, 1.0f);
  r.p = dpp1<Ctrl, RowMask>(v.p, 0.0f);
  r.q = dpp1<Ctrl, RowMask>(v.q, 0.0f);
  return r;
}

// Canonical GCN wave64 inclusive scan: row_shr 1/2/4/8, bcast15 -> rows 1&3,
// bcast31 -> rows 2&3. 36 v_mov_dpp total, zero DS ops.
__device__ __forceinline__ Xf wave_incl_scan(Xf x) {
  x = comp(dpp_xf<0x111, 0xf>(x), x);  // row_shr:1
  x = comp(dpp_xf<0x112, 0xf>(x), x);  // row_shr:2
  x = comp(dpp_xf<0x114, 0xf>(x), x);  // row_shr:4
  x = comp(dpp_xf<0x118, 0xf>(x), x);  // row_shr:8
  x = comp(dpp_xf<0x142, 0xa>(x), x);  // row_bcast:15 -> rows 1,3
  x = comp(dpp_xf<0x143, 0xc>(x), x);  // row_bcast:31 -> rows 2,3
  return x;
}

// 32-element inclusive scan (lanes 0..31 hold data, others identity):
// shr1/2/4/8 within rows + bcast15 row0->row1. 30 v_mov_dpp.
__device__ __forceinline__ Xf scan32(Xf x) {
  x = comp(dpp_xf<0x111, 0xf>(x), x);
  x = comp(dpp_xf<0x112, 0xf>(x), x);
  x = comp(dpp_xf<0x114, 0xf>(x), x);
  x = comp(dpp_xf<0x118, 0xf>(x), x);
  x = comp(dpp_xf<0x142, 0xa>(x), x);  // lane15 -> row1 (rows 3 harmless)
  return x;
}

__device__ __forceinline__ Xf readlane_xf(const Xf& v, int l) {
  Xf r;
  r.a = __int_as_float(__builtin_amdgcn_readlane(__float_as_int(v.a), l));
  r.b = __int_as_float(__builtin_amdgcn_readlane(__float_as_int(v.b), l));
  r.c = __int_as_float(__builtin_amdgcn_readlane(__float_as_int(v.c), l));
  r.d = __int_as_float(__builtin_amdgcn_readlane(__float_as_int(v.d), l));
  r.p = __int_as_float(__builtin_amdgcn_readlane(__float_as_int(v.p), l));
  r.q = __int_as_float(__builtin_amdgcn_readlane(__float_as_int(v.q), l));
  return r;
}

__device__ __forceinline__ Xf make_xf(const float4 xv, float d0, float d1,
                                      float A00, float A01, float A10, float A11,
                                      float C00, float C01, float C10, float C11) {
  Xf m;
  m.a = 1.0f + kDT * (A00 - (xv.x * C00 + xv.y * C10));
  m.b =        kDT * (A01 - (xv.x * C01 + xv.y * C11));
  m.c =        kDT * (A10 - (xv.z * C00 + xv.w * C10));
  m.d = 1.0f + kDT * (A11 - (xv.z * C01 + xv.w * C11));
  m.p = xv.x * d0 + xv.y * d1;
  m.q = xv.z * d0 + xv.w * d1;
  return m;
}

// One block per row. 4 sub-passes of 2048 steps (2 consecutive steps/thread,
// 32B lane stride — R12's proven pattern), grouped in PAIRS between barriers:
// 2 barriers per row instead of 4. One 32-element DPP stitch per group covers
// both sub-passes. __launch_bounds__(1024,8) pins VGPR<=64 so 2 blocks/CU
// co-reside; the sibling block hides barrier/latency stalls.
__global__ __launch_bounds__(kThreads, 8) void k_fused(
    const float* __restrict__ xic, const float* __restrict__ dy,
    const float* __restrict__ Ap, const float* __restrict__ Cp,
    float* __restrict__ out) {
  __shared__ float sWT[2][2][kWaves][6];   // [group][sub-pass][wave][6]

  const int tid = threadIdx.x;
  const int lane = tid & 63;
  const int w = tid >> 6;
  const size_t rbase = (size_t)blockIdx.x * kT;        // xic float4 index
  const size_t rbase2 = (size_t)blockIdx.x * (kT / 2); // dy/out float4 index

  const float4* X4 = reinterpret_cast<const float4*>(xic);
  const float4* D4 = reinterpret_cast<const float4*>(dy);
  float4* O4 = reinterpret_cast<float4*>(out);

  const float A00 = Ap[0], A01 = Ap[1], A10 = Ap[2], A11 = Ap[3];
  const float C00 = Cp[0], C01 = Cp[1], C10 = Cp[2], C11 = Cp[3];

  float x0 = 1.0f, x1 = 0.0f;  // row state entering current group

#pragma unroll
  for (int g = 0; g < 2; ++g) {
    // ---- sub-pass 0 of this group ----
    const size_t xb0i = rbase + (size_t)(2 * g) * 2048 + 2 * tid;
    const size_t db0i = rbase2 + (size_t)(2 * g) * 1024 + tid;
    const float4 xa0 = X4[xb0i];
    const float4 xb0 = X4[xb0i + 1];
    const float4 dv0 = D4[db0i];

    const Xf s0_0 = make_xf(xa0, dv0.x, dv0.y,
                            A00, A01, A10, A11, C00, C01, C10, C11);
    const Xf s1_0 = make_xf(xb0, dv0.z, dv0.w,
                            A00, A01, A10, A11, C00, C01, C10, C11);

    // ---- issue sub-pass 1 loads early ----
    const size_t xb1i = rbase + (size_t)(2 * g + 1) * 2048 + 2 * tid;
    const size_t db1i = rbase2 + (size_t)(2 * g + 1) * 1024 + tid;
    const float4 xa1 = X4[xb1i];
    const float4 xb1 = X4[xb1i + 1];
    const float4 dv1 = D4[db1i];

    // ---- scan sub-pass 0 ----
    const Xf inc0 = wave_incl_scan(comp(s0_0, s1_0));
    const Xf le0 = dpp_xf<0x138, 0xf>(inc0);   // WF_SR1: lane-exclusive
    if (lane == 63) {
      sWT[g][0][w][0] = inc0.a; sWT[g][0][w][1] = inc0.b;
      sWT[g][0][w][2] = inc0.c; sWT[g][0][w][3] = inc0.d;
      sWT[g][0][w][4] = inc0.p; sWT[g][0][w][5] = inc0.q;
    }

    // ---- sub-pass 1 transforms + scan ----
    const Xf s0_1 = make_xf(xa1, dv1.x, dv1.y,
                            A00, A01, A10, A11, C00, C01, C10, C11);
    const Xf s1_1 = make_xf(xb1, dv1.z, dv1.w,
                            A00, A01, A10, A11, C00, C01, C10, C11);
    const Xf inc1 = wave_incl_scan(comp(s0_1, s1_1));
    const Xf le1 = dpp_xf<0x138, 0xf>(inc1);
    if (lane == 63) {
      sWT[g][1][w][0] = inc1.a; sWT[g][1][w][1] = inc1.b;
      sWT[g][1][w][2] = inc1.c; sWT[g][1][w][3] = inc1.d;
      sWT[g][1][w][4] = inc1.p; sWT[g][1][w][5] = inc1.q;
    }
    __syncthreads();   // the ONLY barrier this group

    // ---- stitch: lanes 0..31 hold the 32 (sub-pass, wave) totals ----
    Xf v{1.f, 0.f, 0.f, 1.f, 0.f, 0.f};
    if (lane < 32) {
      const int sp = lane >> 4, wl = lane & 15;
      v = Xf{sWT[g][sp][wl][0], sWT[g][sp][wl][1], sWT[g][sp][wl][2],
             sWT[g][sp][wl][3], sWT[g][sp][wl][4], sWT[g][sp][wl][5]};
    }
    v = scan32(v);
    const Xf TT = readlane_xf(v, 31);   // group total (4096 steps)

    // ---- emit sub-pass 0 ----
    {
      Xf Ew{1.f, 0.f, 0.f, 1.f, 0.f, 0.f};
      if (w > 0) Ew = readlane_xf(v, w - 1);
      const Xf ex = comp(Ew, le0);
      float e0 = ex.a * x0 + ex.b * x1 + ex.p;
      float e1 = ex.c * x0 + ex.d * x1 + ex.q;
      float4 o;
      o.x = kDT * (C00 * e0 + C01 * e1);
      o.y = kDT * (C10 * e0 + C11 * e1);
      const float n0 = s0_0.a * e0 + s0_0.b * e1 + s0_0.p;
      const float n1 = s0_0.c * e0 + s0_0.d * e1 + s0_0.q;
      o.z = kDT * (C00 * n0 + C01 * n1);
      o.w = kDT * (C10 * n0 + C11 * n1);
      O4[db0i] = o;
    }

    // ---- emit sub-pass 1 ----
    {
      const Xf Ew = readlane_xf(v, 15 + w);   // w==0 -> sub-pass-0 total
      const Xf ex = comp(Ew, le1);
      float e0 = ex.a * x0 + ex.b * x1 + ex.p;
      float e1 = ex.c * x0 + ex.d * x1 + ex.q;
      float4 o;
      o.x = kDT * (C00 * e0 + C01 * e1);
      o.y = kDT * (C10 * e0 + C11 * e1);
      const float n0 = s0_1.a * e0 + s0_1.b * e1 + s0_1.p;
      const float n1 = s0_1.c * e0 + s0_1.d * e1 + s0_1.q;
      o.z = kDT * (C00 * n0 + C01 * n1);
      o.w = kDT * (C10 * n0 + C11 * n1);
      O4[db1i] = o;
    }

    // ---- advance row state by the whole group ----
    if (g == 0) {
      const float n0 = TT.a * x0 + TT.b * x1 + TT.p;
      const float n1 = TT.c * x0 + TT.d * x1 + TT.q;
      x0 = n0; x1 = n1;
    }
  }
}

}  // namespace

extern "C" void kernel_launch(void* const* d_in, const int* in_sizes, int n_in,
                              void* d_out, int out_size, void* d_ws,
                              size_t ws_size, hipStream_t stream) {
  const float* xic = (const float*)d_in[0];  // [B,T,2,2]
  const float* dy  = (const float*)d_in[1];  // [B,T,2]
  const float* Ap  = (const float*)d_in[2];  // [2,2] coeffs_A
  const float* Cp  = (const float*)d_in[3];  // [2,2] C
  float* out = (float*)d_out;                // [B,T,2]

  k_fused<<<kB, kThreads, 0, stream>>>(xic, dy, Ap, Cp, out);
}